// Round 8
// baseline (208.083 us; speedup 1.0000x reference)
//
#include <hip/hip_runtime.h>
#include <hip/hip_fp16.h>
#include <cmath>

// MLDR loss on MI355X, v7.1: scan-free streaming kernels (fix: __exp2f ->
// __builtin_amdgcn_exp2f; glibc macro collision).
//  K1:  raw -> SQ fp16 (clipped squares, 32 MB) + L (per-32-sample local EMA
//       end states, 24 series x 4 sigs, 12.6 MB).
//  K2a: within-chunk serial scan over 128 segments -> P (carry at each
//       segment start, 12.6 MB) + Y0 (chunk totals).
//  K2b: cross-chunk serial scan -> Y (state at end of each chunk).
//  K3:  streaming (no scan): carry = P + Y*exp2(l2a*sic); 12 long states;
//       emits Etab[24][65536] log-ratios at 16-sample granularity (6 MB).
//  K4:  streaming, one pair per block-z: 4 states; D=log(yp/yt) per sample;
//       E via register lerp of 4 preloaded table values; reduce -> part.
//  K5:  fp64 sum / (8*T).
// c-scale cancels in log ratios -> unscaled recurrences. fp16 squares:
// clip floor 6.2e-5 (fp16-normal-safe; loss bias ~4e-6 vs 2.8e-3 threshold).

#define T_LEN   1048576
#define G       32
#define SEGS    32768       // per sig
#define CSEGS   128         // segments per chunk
#define CHUNKS  256
#define COLS    65536
#define JMAX    65535
#define FLOOR16 6.2e-5f

struct K1A  { float d[6]; };
struct K2aA { float aG[6]; };    // d^32
struct K2bA { float dC[6]; };    // d^4096
struct K3A  { float d[3]; float l2a[3]; };  // long coefs
struct K4A  { float d[3]; float l2a[3]; };  // short coefs

// ---------------- K1: squares->fp16 + local EMA states ----------------
__global__ __launch_bounds__(256)
void k1_stage(const float* __restrict__ xp, const float* __restrict__ xt,
              __half* __restrict__ SQ, float* __restrict__ L, K1A ka)
{
  int sig = blockIdx.y;
  int gseg = blockIdx.x * 256 + threadIdx.x;
  long base = (long)gseg * G;
  const float* p0 = xp + (long)sig * 2 * T_LEN;
  const float* p1 = p0 + T_LEN;
  const float* t0 = xt + (long)sig * 2 * T_LEN;
  const float* t1 = t0 + T_LEN;

  float v[24];
#pragma unroll
  for (int j = 0; j < 24; j++) v[j] = 0.f;

#pragma unroll
  for (int tile = 0; tile < 4; tile++) {
    long o = base + tile * 8;
    float4 A0 = *(const float4*)(p0 + o), A1 = *(const float4*)(p0 + o + 4);
    float4 B0 = *(const float4*)(p1 + o), B1 = *(const float4*)(p1 + o + 4);
    float4 C0 = *(const float4*)(t0 + o), C1 = *(const float4*)(t0 + o + 4);
    float4 D0 = *(const float4*)(t1 + o), D1 = *(const float4*)(t1 + o + 4);
    float q[4][8];
    float m;
#define QQ(i, AV, BV, CV, DV, CMP) \
    m = AV.CMP + BV.CMP; q[0][i] = fmaxf(0.5f * m * m, FLOOR16); \
    m = AV.CMP - BV.CMP; q[1][i] = fmaxf(0.5f * m * m, FLOOR16); \
    m = CV.CMP + DV.CMP; q[2][i] = fmaxf(0.5f * m * m, FLOOR16); \
    m = CV.CMP - DV.CMP; q[3][i] = fmaxf(0.5f * m * m, FLOOR16);
    QQ(0,A0,B0,C0,D0,x) QQ(1,A0,B0,C0,D0,y) QQ(2,A0,B0,C0,D0,z) QQ(3,A0,B0,C0,D0,w)
    QQ(4,A1,B1,C1,D1,x) QQ(5,A1,B1,C1,D1,y) QQ(6,A1,B1,C1,D1,z) QQ(7,A1,B1,C1,D1,w)
#undef QQ
    // round to fp16, store, and use the ROUNDED values in the EMA so the
    // carry chain is exactly consistent with k3/k4's streaming.
#pragma unroll
    for (int st = 0; st < 4; st++) {
      unsigned w4[4];
      float fr[8];
#pragma unroll
      for (int h = 0; h < 4; h++) {
        __half2 h2 = __floats2half2_rn(q[st][2*h], q[st][2*h+1]);
        w4[h] = *reinterpret_cast<unsigned*>(&h2);
        float2 f2 = __half22float2(h2);
        fr[2*h] = f2.x; fr[2*h+1] = f2.y;
      }
      uint4 u; u.x = w4[0]; u.y = w4[1]; u.z = w4[2]; u.w = w4[3];
      *(uint4*)(SQ + ((long)(sig*4+st)) * T_LEN + o) = u;
#pragma unroll
      for (int i = 0; i < 8; i++) q[st][i] = fr[i];
    }
#pragma unroll
    for (int i = 0; i < 8; i++) {
#pragma unroll
      for (int cf = 0; cf < 6; cf++) {
        float dd = ka.d[cf];
        v[cf*4+0] = fmaf(dd, v[cf*4+0], q[0][i]);
        v[cf*4+1] = fmaf(dd, v[cf*4+1], q[1][i]);
        v[cf*4+2] = fmaf(dd, v[cf*4+2], q[2][i]);
        v[cf*4+3] = fmaf(dd, v[cf*4+3], q[3][i]);
      }
    }
  }
  float4* Lp = (float4*)(L + ((long)sig * SEGS + gseg) * 24);
#pragma unroll
  for (int cf = 0; cf < 6; cf++) {
    float4 f; f.x = v[cf*4+0]; f.y = v[cf*4+1]; f.z = v[cf*4+2]; f.w = v[cf*4+3];
    Lp[cf] = f;
  }
}

// ---------------- K2a: within-chunk prefix ----------------
__global__ __launch_bounds__(256)
void k2a_scan(const float* __restrict__ L, float* __restrict__ P,
              float* __restrict__ Y0, K2aA ka)
{
  int sig = blockIdx.y;
  int lt = threadIdx.x & 31, grp = threadIdx.x >> 5;
  int chunk = blockIdx.x * 8 + grp;
  if (lt >= 24) return;
  float a = ka.aG[lt >> 2];
  float S = 0.f;
  long rowbase = ((long)sig * SEGS + (long)chunk * CSEGS) * 24 + lt;
#pragma unroll 8
  for (int s = 0; s < CSEGS; s++) {
    long idx = rowbase + (long)s * 24;
    P[idx] = S;                      // state at end of previous segment
    S = fmaf(S, a, L[idx]);
  }
  Y0[((long)sig * CHUNKS + chunk) * 24 + lt] = S;
}

// ---------------- K2b: cross-chunk scan ----------------
__global__ void k2b_scan(const float* __restrict__ Y0, float* __restrict__ Y, K2bA ka)
{
  int t = threadIdx.x;
  if (t >= 96) return;
  int sig = t / 24, j = t % 24;
  float dC = ka.dC[j >> 2];
  float y = 0.f;
#pragma unroll 8
  for (int c = 0; c < CHUNKS; c++) {
    long idx = ((long)sig * CHUNKS + c) * 24 + j;
    y = fmaf(y, dC, Y0[idx]);
    Y[idx] = y;                      // state at END of chunk c
  }
}

// ---------------- K3: streaming long-coef table ----------------
__global__ __launch_bounds__(256)
void k3_table(const __half* __restrict__ SQ, const float* __restrict__ P,
              const float* __restrict__ Y, float* __restrict__ Etab, K3A ka)
{
  int sig = blockIdx.y;
  int gseg = blockIdx.x * 256 + threadIdx.x;
  int chunk = gseg >> 7, sic = gseg & 127;
  long base = (long)gseg * G;

  float y[12];
  const float* Pb = P + ((long)sig * SEGS + gseg) * 24;
  const float* Yb = Y + ((long)sig * CHUNKS + (chunk - 1)) * 24;
#pragma unroll
  for (int k = 0; k < 3; k++) {
    float4 p4 = *(const float4*)(Pb + (2*k+1)*4);
    float pw = __builtin_amdgcn_exp2f(ka.l2a[k] * (float)sic);
    float4 y4 = {0.f, 0.f, 0.f, 0.f};
    if (chunk > 0) y4 = *(const float4*)(Yb + (2*k+1)*4);
    y[4*k+0] = fmaf(y4.x, pw, p4.x);
    y[4*k+1] = fmaf(y4.y, pw, p4.y);
    y[4*k+2] = fmaf(y4.z, pw, p4.z);
    y[4*k+3] = fmaf(y4.w, pw, p4.w);
  }

  const __half* s0 = SQ + ((long)(sig*4+0)) * T_LEN + base;
  const __half* s1 = SQ + ((long)(sig*4+1)) * T_LEN + base;
  const __half* s2 = SQ + ((long)(sig*4+2)) * T_LEN + base;
  const __half* s3 = SQ + ((long)(sig*4+3)) * T_LEN + base;

  float e15[6], e31[6];
#pragma unroll
  for (int tile = 0; tile < 4; tile++) {
    uint4 w0 = *(const uint4*)(s0 + tile*8);
    uint4 w1 = *(const uint4*)(s1 + tile*8);
    uint4 w2 = *(const uint4*)(s2 + tile*8);
    uint4 w3 = *(const uint4*)(s3 + tile*8);
    float f[4][8];
#pragma unroll
    for (int h = 0; h < 4; h++) {
      unsigned a0 = (&w0.x)[h], a1 = (&w1.x)[h], a2 = (&w2.x)[h], a3 = (&w3.x)[h];
      float2 g;
      g = __half22float2(*reinterpret_cast<__half2*>(&a0)); f[0][2*h] = g.x; f[0][2*h+1] = g.y;
      g = __half22float2(*reinterpret_cast<__half2*>(&a1)); f[1][2*h] = g.x; f[1][2*h+1] = g.y;
      g = __half22float2(*reinterpret_cast<__half2*>(&a2)); f[2][2*h] = g.x; f[2][2*h+1] = g.y;
      g = __half22float2(*reinterpret_cast<__half2*>(&a3)); f[3][2*h] = g.x; f[3][2*h+1] = g.y;
    }
#pragma unroll
    for (int i = 0; i < 8; i++) {
#pragma unroll
      for (int k = 0; k < 3; k++) {
        float dd = ka.d[k];
        y[4*k+0] = fmaf(dd, y[4*k+0], f[0][i]);
        y[4*k+1] = fmaf(dd, y[4*k+1], f[1][i]);
        y[4*k+2] = fmaf(dd, y[4*k+2], f[2][i]);
        y[4*k+3] = fmaf(dd, y[4*k+3], f[3][i]);
      }
    }
    if (tile == 1 || tile == 3) {
      float* dst = (tile == 1) ? e15 : e31;
#pragma unroll
      for (int k = 0; k < 3; k++) {
        dst[2*k+0] = __logf(__fdividef(y[4*k+0], y[4*k+2]));
        dst[2*k+1] = __logf(__fdividef(y[4*k+1], y[4*k+3]));
      }
    }
  }
  long col0 = (long)gseg * 2;
#pragma unroll
  for (int k = 0; k < 3; k++) {
#pragma unroll
    for (int st = 0; st < 2; st++) {
      float2 o; o.x = e15[2*k+st]; o.y = e31[2*k+st];
      *(float2*)(Etab + (long)(k*8 + sig*2 + st) * COLS + col0) = o;
    }
  }
}

// ---------------- K4: streaming short-coef + lerp + reduce ----------------
__global__ __launch_bounds__(256)
void k4_main(const __half* __restrict__ SQ, const float* __restrict__ P,
             const float* __restrict__ Y, const float* __restrict__ Etab,
             float* __restrict__ part, K4A ka)
{
  int sig = blockIdx.y, pk = blockIdx.z;
  int gseg = blockIdx.x * 256 + threadIdx.x;
  int chunk = gseg >> 7, sic = gseg & 127;
  long base = (long)gseg * G;
  float d = ka.d[pk];

  float4 p4 = *(const float4*)(P + ((long)sig * SEGS + gseg) * 24 + pk * 8);
  float pw = __builtin_amdgcn_exp2f(ka.l2a[pk] * (float)sic);
  float4 yc = {0.f, 0.f, 0.f, 0.f};
  if (chunk > 0)
    yc = *(const float4*)(Y + ((long)sig * CHUNKS + (chunk - 1)) * 24 + pk * 8);
  float y0 = fmaf(yc.x, pw, p4.x), y1 = fmaf(yc.y, pw, p4.y);
  float y2 = fmaf(yc.z, pw, p4.z), y3 = fmaf(yc.w, pw, p4.w);

  const int sh = (pk == 0) ? 10804 : ((pk == 1) ? 31972 : 63945);
  const float* Tm = Etab + (long)(pk*8 + sig*2) * COLS;
  const float* Ts = Tm + COLS;
  int u0 = (int)base + sh; if (u0 >= T_LEN) u0 -= T_LEN;
  int qm0 = u0 - 15, j0 = qm0 >> 4;
  bool fast = (qm0 >= 0) && (u0 + 31 < T_LEN) && (j0 <= JMAX - 3);
  float tm[4], tsv[4];
  if (fast) {
#pragma unroll
    for (int i = 0; i < 4; i++) { tm[i] = Tm[j0 + i]; tsv[i] = Ts[j0 + i]; }
  }

  const __half* s0 = SQ + ((long)(sig*4+0)) * T_LEN + base;
  const __half* s1 = SQ + ((long)(sig*4+1)) * T_LEN + base;
  const __half* s2 = SQ + ((long)(sig*4+2)) * T_LEN + base;
  const __half* s3 = SQ + ((long)(sig*4+3)) * T_LEN + base;

  float acc = 0.f;
#pragma unroll
  for (int tile = 0; tile < 4; tile++) {
    uint4 w0 = *(const uint4*)(s0 + tile*8);
    uint4 w1 = *(const uint4*)(s1 + tile*8);
    uint4 w2 = *(const uint4*)(s2 + tile*8);
    uint4 w3 = *(const uint4*)(s3 + tile*8);
    float f[4][8];
#pragma unroll
    for (int h = 0; h < 4; h++) {
      unsigned a0 = (&w0.x)[h], a1 = (&w1.x)[h], a2 = (&w2.x)[h], a3 = (&w3.x)[h];
      float2 g;
      g = __half22float2(*reinterpret_cast<__half2*>(&a0)); f[0][2*h] = g.x; f[0][2*h+1] = g.y;
      g = __half22float2(*reinterpret_cast<__half2*>(&a1)); f[1][2*h] = g.x; f[1][2*h+1] = g.y;
      g = __half22float2(*reinterpret_cast<__half2*>(&a2)); f[2][2*h] = g.x; f[2][2*h+1] = g.y;
      g = __half22float2(*reinterpret_cast<__half2*>(&a3)); f[3][2*h] = g.x; f[3][2*h+1] = g.y;
    }
#pragma unroll
    for (int i = 0; i < 8; i++) {
      int idx = tile * 8 + i;
      y0 = fmaf(d, y0, f[0][i]); y1 = fmaf(d, y1, f[1][i]);
      y2 = fmaf(d, y2, f[2][i]); y3 = fmaf(d, y3, f[3][i]);
      float Dm = __logf(__fdividef(y0, y2));
      float Ds = __logf(__fdividef(y1, y3));
      float em, es;
      if (fast) {
        int q = qm0 + idx;
        int jj = (q >> 4) - j0;
        float fr = (float)(q & 15) * 0.0625f;
        float am = (jj == 0) ? tm[0] : ((jj == 1) ? tm[1] : tm[2]);
        float bm = (jj == 0) ? tm[1] : ((jj == 1) ? tm[2] : tm[3]);
        float as = (jj == 0) ? tsv[0] : ((jj == 1) ? tsv[1] : tsv[2]);
        float bs = (jj == 0) ? tsv[1] : ((jj == 1) ? tsv[2] : tsv[3]);
        em = fmaf(fr, bm - am, am);
        es = fmaf(fr, bs - as, as);
      } else {
        int u = u0 + idx; if (u >= T_LEN) u -= T_LEN;
        int qq = u - 15;
        if (qq < 0) { em = Tm[0]; es = Ts[0]; }
        else {
          int j = qq >> 4;
          if (j >= JMAX) { em = Tm[JMAX]; es = Ts[JMAX]; }
          else {
            float fr = (float)(qq & 15) * 0.0625f;
            float a = Tm[j], b = Tm[j+1];
            em = fmaf(fr, b - a, a);
            a = Ts[j]; b = Ts[j+1];
            es = fmaf(fr, b - a, a);
          }
        }
      }
      acc += fabsf(Dm - em) + fabsf(Ds - es);
    }
  }

#pragma unroll
  for (int off = 32; off > 0; off >>= 1) acc += __shfl_down(acc, off, 64);
  __shared__ float psum[4];
  int lane = threadIdx.x & 63, w = threadIdx.x >> 6;
  if (lane == 0) psum[w] = acc;
  __syncthreads();
  if (threadIdx.x == 0)
    part[(pk * 4 + sig) * 128 + blockIdx.x] = psum[0] + psum[1] + psum[2] + psum[3];
}

__global__ void k5_final(const float* __restrict__ part, float* __restrict__ out)
{
  __shared__ double lds[256];
  int tid = threadIdx.x;
  double s = 0.0;
  for (int i = tid; i < 1536; i += 256) s += (double)part[i];
  lds[tid] = s; __syncthreads();
  for (int o = 128; o > 0; o >>= 1) {
    if (tid < o) lds[tid] += lds[tid + o];
    __syncthreads();
  }
  if (tid == 0) out[0] = (float)(lds[0] * (1.0 / (8.0 * 1048576.0)));
}

extern "C" void kernel_launch(void* const* d_in, const int* in_sizes, int n_in,
                              void* d_out, int out_size, void* d_ws, size_t ws_size,
                              hipStream_t stream)
{
  (void)in_sizes; (void)n_in; (void)out_size; (void)ws_size;
  const float* xp = (const float*)d_in[0];
  const float* xt = (const float*)d_in[1];
  float* out = (float*)d_out;
  char* ws = (char*)d_ws;

  __half* SQ   = (__half*)(ws);                       // 33554432
  float*  L    = (float*)(ws + 33554432);             // 12582912
  float*  P    = (float*)(ws + 46137344);             // 12582912
  float*  Y0   = (float*)(ws + 58720256);             // 98304
  float*  Yb   = (float*)(ws + 58818560);             // 98304
  float*  Etab = (float*)(ws + 58916864);             // 6291456
  float*  part = (float*)(ws + 65208320);             // 6144

  static const double S_MS[3] = {10.0, 50.0, 100.0};
  static const double L_MS[3] = {500.0, 1500.0, 3000.0};

  K1A k1a; K2aA k2aa; K2bA k2ba; K3A k3a; K4A k4a;
  for (int k = 0; k < 3; k++) {
    for (int which = 0; which < 2; which++) {
      int idx = 2 * k + which;
      double ms = which ? L_MS[k] : S_MS[k];
      float cF = (float)(1.0 - std::exp(-2200.0 / (ms * 44100.0)));
      float dF = 1.0f - cF;               // exact fp32 match to reference
      k1a.d[idx] = dF;
      double a32 = std::pow((double)dF, 32.0);
      k2aa.aG[idx] = (float)a32;
      k2ba.dC[idx] = (float)std::pow((double)dF, 4096.0);
      float l2a = (float)(std::log2(a32));
      if (which) { k3a.d[k] = dF; k3a.l2a[k] = l2a; }
      else       { k4a.d[k] = dF; k4a.l2a[k] = l2a; }
    }
  }

  k1_stage<<<dim3(128, 4), 256, 0, stream>>>(xp, xt, SQ, L, k1a);
  k2a_scan<<<dim3(32, 4), 256, 0, stream>>>(L, P, Y0, k2aa);
  k2b_scan<<<1, 128, 0, stream>>>(Y0, Yb, k2ba);
  k3_table<<<dim3(128, 4), 256, 0, stream>>>(SQ, P, Yb, Etab, k3a);
  k4_main<<<dim3(128, 4, 3), 256, 0, stream>>>(SQ, P, Yb, Etab, part, k4a);
  k5_final<<<1, 256, 0, stream>>>(part, out);
}